// Round 1
// baseline (4638.996 us; speedup 1.0000x reference)
//
#include <hip/hip_runtime.h>
#include <math.h>

#define D 256
#define TM 64     // rows per GEMM block
#define KT 32     // K tile

// ---------------- count + recip ----------------
__global__ __launch_bounds__(256) void count_kernel(const int* __restrict__ dst1, int E1,
                                                    const int* __restrict__ dst2, int E2,
                                                    float* cnt1, float* cnt2) {
    int t = blockIdx.x * 256 + threadIdx.x;
    if (t < E1) {
        atomicAdd(&cnt1[dst1[t]], 1.0f);
    } else if (t < E1 + E2) {
        atomicAdd(&cnt2[dst2[t - E1]], 1.0f);
    }
}

__global__ __launch_bounds__(256) void recip_kernel(float* cnt1, int n1, float* cnt2, int n2) {
    int t = blockIdx.x * 256 + threadIdx.x;
    if (t < n1) {
        cnt1[t] = 1.0f / fmaxf(cnt1[t], 1.0f);
    } else if (t < n1 + n2) {
        cnt2[t - n1] = 1.0f / fmaxf(cnt2[t - n1], 1.0f);
    }
}

// ---------------- scatter-add aggregate ----------------
// one wave (64 lanes) per edge; each lane handles one float4 of the 256-dim row
__global__ __launch_bounds__(256) void scatter_kernel(const float* __restrict__ x,
                                                      const int* __restrict__ src,
                                                      const int* __restrict__ dst,
                                                      float* __restrict__ agg, int E) {
    int t = blockIdx.x * 256 + threadIdx.x;
    int e = t >> 6;
    int l = t & 63;
    if (e >= E) return;
    int s = src[e];
    int d = dst[e];
    float4 v = *(const float4*)(x + (size_t)s * D + l * 4);
    float* a = agg + (size_t)d * D + l * 4;
    atomicAdd(a + 0, v.x);
    atomicAdd(a + 1, v.y);
    atomicAdd(a + 2, v.z);
    atomicAdd(a + 3, v.w);
}

// ---------------- fused SAGE layer GEMM ----------------
// out[i][j] = tanh( sum_k mean[i][k]*Wl[j][k] + b[j] + sum_k x[i][k]*Wr[j][k] )
// treated as single K=512 GEMM: A' = [agg*recip | xsrc], W' = [Wl | Wr]
// block: 64 rows x 256 cols; thread: 4 rows x 16 cols. In-place (out may == agg):
// each block covers ALL cols of its rows, writes only in epilogue -> safe.
__global__ __launch_bounds__(256) void sage_gemm(const float* __restrict__ agg,
                                                 const float* __restrict__ recip,
                                                 const float* __restrict__ xsrc,
                                                 const float* __restrict__ Wl,
                                                 const float* __restrict__ bias,
                                                 const float* __restrict__ Wr,
                                                 float* __restrict__ out) {
    __shared__ float As[TM][KT + 4];     // row stride 36 floats (144 B, 16B-aligned)
    __shared__ float Ws[KT][D + 4];      // row stride 260 floats (1040 B, 16B-aligned)

    const int tid = threadIdx.x;
    const size_t row0 = (size_t)blockIdx.x * TM;

    const int tc = tid & 15;       // col group 0..15
    const int tr = tid >> 4;       // row group 0..15
    const int rbase = tr * 4;      // local rows rbase..rbase+3
    const int cbase = tc * 16;     // cols cbase..cbase+15

    float acc[4][16];
#pragma unroll
    for (int i = 0; i < 4; ++i)
#pragma unroll
        for (int j = 0; j < 16; ++j) acc[i][j] = 0.0f;

    const int skq = tid & 7;       // k-quad 0..7
    const int srow = tid >> 3;     // 0..31

    for (int kt = 0; kt < 2 * D; kt += KT) {
        const bool first = (kt < D);
        const int kg = first ? kt : kt - D;
        const int k = kg + skq * 4;

        // ---- stage A tile (rows srow, srow+32) ----
#pragma unroll
        for (int p = 0; p < 2; ++p) {
            int r = srow + p * 32;
            size_t gr = row0 + r;
            float4 v;
            if (first) {
                v = *(const float4*)(agg + gr * D + k);
                float s = recip[gr];
                v.x *= s; v.y *= s; v.z *= s; v.w *= s;
            } else {
                v = *(const float4*)(xsrc + gr * D + k);
            }
            *(float4*)&As[r][skq * 4] = v;
        }

        // ---- stage W tile (transpose to k-major) ----
        const float* W = first ? Wl : Wr;
#pragma unroll
        for (int jj = 0; jj < 8; ++jj) {
            int j = srow + 32 * jj;
            float4 w = *(const float4*)(W + (size_t)j * D + k);
            int kk = skq * 4;
            Ws[kk + 0][j] = w.x;
            Ws[kk + 1][j] = w.y;
            Ws[kk + 2][j] = w.z;
            Ws[kk + 3][j] = w.w;
        }

        __syncthreads();

#pragma unroll 8
        for (int kk = 0; kk < KT; ++kk) {
            float a[4];
#pragma unroll
            for (int i = 0; i < 4; ++i) a[i] = As[rbase + i][kk];
            float w[16];
#pragma unroll
            for (int q = 0; q < 4; ++q) {
                float4 wv = *(const float4*)&Ws[kk][cbase + q * 4];
                w[q * 4 + 0] = wv.x;
                w[q * 4 + 1] = wv.y;
                w[q * 4 + 2] = wv.z;
                w[q * 4 + 3] = wv.w;
            }
#pragma unroll
            for (int i = 0; i < 4; ++i)
#pragma unroll
                for (int j = 0; j < 16; ++j)
                    acc[i][j] += a[i] * w[j];
        }

        __syncthreads();
    }

    // ---- epilogue: bias + tanh + store ----
#pragma unroll
    for (int i = 0; i < 4; ++i) {
        size_t gr = row0 + rbase + i;
#pragma unroll
        for (int q = 0; q < 4; ++q) {
            float4 o;
            o.x = tanhf(acc[i][q * 4 + 0] + bias[cbase + q * 4 + 0]);
            o.y = tanhf(acc[i][q * 4 + 1] + bias[cbase + q * 4 + 1]);
            o.z = tanhf(acc[i][q * 4 + 2] + bias[cbase + q * 4 + 2]);
            o.w = tanhf(acc[i][q * 4 + 3] + bias[cbase + q * 4 + 3]);
            *(float4*)(out + gr * D + cbase + q * 4) = o;
        }
    }
}

extern "C" void kernel_launch(void* const* d_in, const int* in_sizes, int n_in,
                              void* d_out, int out_size, void* d_ws, size_t ws_size,
                              hipStream_t stream) {
    const float* nodes = (const float*)d_in[0];
    const float* W_l1  = (const float*)d_in[1];
    const float* b1    = (const float*)d_in[2];
    const float* W_r1  = (const float*)d_in[3];
    const float* W_l2  = (const float*)d_in[4];
    const float* b2    = (const float*)d_in[5];
    const float* W_r2  = (const float*)d_in[6];
    const int* src1 = (const int*)d_in[7];
    const int* dst1 = (const int*)d_in[8];
    const int* src2 = (const int*)d_in[9];
    const int* dst2 = (const int*)d_in[10];

    const int E1 = in_sizes[7];
    const int E2 = in_sizes[9];
    const int N1 = 40000;  // fixed problem size (n1 lives on device; constants per reference)
    const int N2 = 8000;

    float* agg1 = (float*)d_ws;                       // N1*D floats (becomes h1 in place)
    float* cnt1 = agg1 + (size_t)N1 * D;              // N1 floats (becomes recip1)
    float* cnt2 = cnt1 + N1;                          // N2 floats (becomes recip2)
    float* outp = (float*)d_out;                      // N2*D (agg2, then h2 in place)

    size_t zbytes = ((size_t)N1 * D + N1 + N2) * sizeof(float);
    hipMemsetAsync(d_ws, 0, zbytes, stream);
    hipMemsetAsync(d_out, 0, (size_t)N2 * D * sizeof(float), stream);

    {
        int tot = E1 + E2;
        count_kernel<<<(tot + 255) / 256, 256, 0, stream>>>(dst1, E1, dst2, E2, cnt1, cnt2);
    }
    {
        int tot = N1 + N2;
        recip_kernel<<<(tot + 255) / 256, 256, 0, stream>>>(cnt1, N1, cnt2, N2);
    }

    // layer 1
    scatter_kernel<<<(E1 * 64) / 256, 256, 0, stream>>>(nodes, src1, dst1, agg1, E1);
    sage_gemm<<<N1 / TM, 256, 0, stream>>>(agg1, cnt1, nodes, W_l1, b1, W_r1, agg1);

    // layer 2
    scatter_kernel<<<(E2 * 64) / 256, 256, 0, stream>>>(agg1, src2, dst2, outp, E2);
    sage_gemm<<<N2 / TM, 256, 0, stream>>>(outp, cnt2, agg1, W_l2, b2, W_r2, outp);
}

// Round 2
// 968.060 us; speedup vs baseline: 4.7921x; 4.7921x over previous
//
#include <hip/hip_runtime.h>
#include <math.h>

#define D 256
#define TM 64     // rows per GEMM block
#define KT 32     // K tile

// ---------------- int histogram of dst ----------------
__global__ __launch_bounds__(256) void hist_kernel(const int* __restrict__ dst1, int E1,
                                                   const int* __restrict__ dst2, int E2,
                                                   int* cnt1, int* cnt2) {
    int t = blockIdx.x * 256 + threadIdx.x;
    if (t < E1) {
        atomicAdd(&cnt1[dst1[t]], 1);
    } else if (t < E1 + E2) {
        atomicAdd(&cnt2[dst2[t - E1]], 1);
    }
}

// ---------------- exclusive scan (one block per array) ----------------
__global__ __launch_bounds__(1024) void scan_kernel(const int* __restrict__ cnt1, int n1, int* off1,
                                                    const int* __restrict__ cnt2, int n2, int* off2) {
    const int* cnt; int n; int* off;
    if (blockIdx.x == 0) { cnt = cnt1; n = n1; off = off1; }
    else                 { cnt = cnt2; n = n2; off = off2; }

    __shared__ int buf[1024];
    __shared__ int base_s;
    const int tid = threadIdx.x;
    if (tid == 0) base_s = 0;
    __syncthreads();

    for (int c0 = 0; c0 < n; c0 += 1024) {
        int i = c0 + tid;
        int v = (i < n) ? cnt[i] : 0;
        buf[tid] = v;
        __syncthreads();
        // Hillis-Steele inclusive scan
        for (int s = 1; s < 1024; s <<= 1) {
            int t = (tid >= s) ? buf[tid - s] : 0;
            __syncthreads();
            buf[tid] += t;
            __syncthreads();
        }
        int incl = buf[tid];
        int b = base_s;
        if (i < n) off[i] = b + incl - v;   // exclusive
        __syncthreads();
        if (tid == 0) base_s = b + buf[1023];
        __syncthreads();
    }
    if (tid == 0) off[n] = base_s;
}

// ---------------- cursors + recip ----------------
__global__ __launch_bounds__(256) void prep_kernel(const int* __restrict__ off1, const int* __restrict__ cnt1,
                                                   int* cur1, float* recip1, int n1,
                                                   const int* __restrict__ off2, const int* __restrict__ cnt2,
                                                   int* cur2, float* recip2, int n2) {
    int t = blockIdx.x * 256 + threadIdx.x;
    if (t < n1) {
        cur1[t] = off1[t];
        recip1[t] = 1.0f / fmaxf((float)cnt1[t], 1.0f);
    } else if (t < n1 + n2) {
        int u = t - n1;
        cur2[u] = off2[u];
        recip2[u] = 1.0f / fmaxf((float)cnt2[u], 1.0f);
    }
}

// ---------------- counting-sort edges by dst ----------------
__global__ __launch_bounds__(256) void sort_kernel(const int* __restrict__ src1, const int* __restrict__ dst1, int E1,
                                                   int* cur1, int* sorted1,
                                                   const int* __restrict__ src2, const int* __restrict__ dst2, int E2,
                                                   int* cur2, int* sorted2) {
    int t = blockIdx.x * 256 + threadIdx.x;
    if (t < E1) {
        int d = dst1[t];
        int p = atomicAdd(&cur1[d], 1);
        sorted1[p] = src1[t];
    } else if (t < E1 + E2) {
        int u = t - E1;
        int d = dst2[u];
        int p = atomicAdd(&cur2[d], 1);
        sorted2[p] = src2[u];
    }
}

// ---------------- gather-aggregate: one wave per target node ----------------
// lanes hold float4 slices of the 256-dim row; loop over the node's edge list.
// writes mean (sum * recip) -> zero atomics.
__global__ __launch_bounds__(256) void aggregate_kernel(const float* __restrict__ x,
                                                        const int* __restrict__ sorted,
                                                        const int* __restrict__ off,
                                                        const float* __restrict__ recip,
                                                        float* __restrict__ agg, int n) {
    int node = blockIdx.x * 4 + (threadIdx.x >> 6);
    if (node >= n) return;
    int l = threadIdx.x & 63;
    int beg = off[node], end = off[node + 1];

    float4 a0 = {0.f, 0.f, 0.f, 0.f};
    float4 a1 = {0.f, 0.f, 0.f, 0.f};
    int e = beg;
    for (; e + 1 < end; e += 2) {
        int s0 = sorted[e];
        int s1 = sorted[e + 1];
        float4 v0 = *(const float4*)(x + (size_t)s0 * D + l * 4);
        float4 v1 = *(const float4*)(x + (size_t)s1 * D + l * 4);
        a0.x += v0.x; a0.y += v0.y; a0.z += v0.z; a0.w += v0.w;
        a1.x += v1.x; a1.y += v1.y; a1.z += v1.z; a1.w += v1.w;
    }
    if (e < end) {
        int s = sorted[e];
        float4 v = *(const float4*)(x + (size_t)s * D + l * 4);
        a0.x += v.x; a0.y += v.y; a0.z += v.z; a0.w += v.w;
    }
    float r = recip[node];
    float4 o;
    o.x = (a0.x + a1.x) * r;
    o.y = (a0.y + a1.y) * r;
    o.z = (a0.z + a1.z) * r;
    o.w = (a0.w + a1.w) * r;
    *(float4*)(agg + (size_t)node * D + l * 4) = o;
}

// ---------------- fused SAGE layer GEMM ----------------
// out[i][j] = tanh( sum_k mean[i][k]*Wl[j][k] + b[j] + sum_k x[i][k]*Wr[j][k] )
// single K=512 GEMM: A' = [mean | xsrc], W' = [Wl | Wr]
// block: 64 rows x 256 cols; thread: 4 rows x 16 cols. In-place safe (epilogue-only writes).
__global__ __launch_bounds__(256) void sage_gemm(const float* __restrict__ mean,
                                                 const float* __restrict__ xsrc,
                                                 const float* __restrict__ Wl,
                                                 const float* __restrict__ bias,
                                                 const float* __restrict__ Wr,
                                                 float* __restrict__ out) {
    __shared__ float As[TM][KT + 4];
    __shared__ float Ws[KT][D + 4];

    const int tid = threadIdx.x;
    const size_t row0 = (size_t)blockIdx.x * TM;

    const int tc = tid & 15;
    const int tr = tid >> 4;
    const int rbase = tr * 4;
    const int cbase = tc * 16;

    float acc[4][16];
#pragma unroll
    for (int i = 0; i < 4; ++i)
#pragma unroll
        for (int j = 0; j < 16; ++j) acc[i][j] = 0.0f;

    const int skq = tid & 7;
    const int srow = tid >> 3;

    for (int kt = 0; kt < 2 * D; kt += KT) {
        const bool first = (kt < D);
        const int kg = first ? kt : kt - D;
        const int k = kg + skq * 4;
        const float* A = first ? mean : xsrc;

#pragma unroll
        for (int p = 0; p < 2; ++p) {
            int r = srow + p * 32;
            size_t gr = row0 + r;
            float4 v = *(const float4*)(A + gr * D + k);
            *(float4*)&As[r][skq * 4] = v;
        }

        const float* W = first ? Wl : Wr;
#pragma unroll
        for (int jj = 0; jj < 8; ++jj) {
            int j = srow + 32 * jj;
            float4 w = *(const float4*)(W + (size_t)j * D + k);
            int kk = skq * 4;
            Ws[kk + 0][j] = w.x;
            Ws[kk + 1][j] = w.y;
            Ws[kk + 2][j] = w.z;
            Ws[kk + 3][j] = w.w;
        }

        __syncthreads();

#pragma unroll 8
        for (int kk = 0; kk < KT; ++kk) {
            float a[4];
#pragma unroll
            for (int i = 0; i < 4; ++i) a[i] = As[rbase + i][kk];
            float w[16];
#pragma unroll
            for (int q = 0; q < 4; ++q) {
                float4 wv = *(const float4*)&Ws[kk][cbase + q * 4];
                w[q * 4 + 0] = wv.x;
                w[q * 4 + 1] = wv.y;
                w[q * 4 + 2] = wv.z;
                w[q * 4 + 3] = wv.w;
            }
#pragma unroll
            for (int i = 0; i < 4; ++i)
#pragma unroll
                for (int j = 0; j < 16; ++j)
                    acc[i][j] += a[i] * w[j];
        }

        __syncthreads();
    }

#pragma unroll
    for (int i = 0; i < 4; ++i) {
        size_t gr = row0 + rbase + i;
#pragma unroll
        for (int q = 0; q < 4; ++q) {
            float4 o;
            o.x = tanhf(acc[i][q * 4 + 0] + bias[cbase + q * 4 + 0]);
            o.y = tanhf(acc[i][q * 4 + 1] + bias[cbase + q * 4 + 1]);
            o.z = tanhf(acc[i][q * 4 + 2] + bias[cbase + q * 4 + 2]);
            o.w = tanhf(acc[i][q * 4 + 3] + bias[cbase + q * 4 + 3]);
            *(float4*)(out + gr * D + cbase + q * 4) = o;
        }
    }
}

extern "C" void kernel_launch(void* const* d_in, const int* in_sizes, int n_in,
                              void* d_out, int out_size, void* d_ws, size_t ws_size,
                              hipStream_t stream) {
    const float* nodes = (const float*)d_in[0];
    const float* W_l1  = (const float*)d_in[1];
    const float* b1    = (const float*)d_in[2];
    const float* W_r1  = (const float*)d_in[3];
    const float* W_l2  = (const float*)d_in[4];
    const float* b2    = (const float*)d_in[5];
    const float* W_r2  = (const float*)d_in[6];
    const int* src1 = (const int*)d_in[7];
    const int* dst1 = (const int*)d_in[8];
    const int* src2 = (const int*)d_in[9];
    const int* dst2 = (const int*)d_in[10];

    const int E1 = in_sizes[7];
    const int E2 = in_sizes[9];
    const int N1 = 40000;
    const int N2 = 8000;

    // workspace layout
    float* agg1   = (float*)d_ws;                         // N1*D floats (becomes h1 in place)
    float* recip1 = agg1 + (size_t)N1 * D;                // N1
    float* recip2 = recip1 + N1;                          // N2
    int*   cnt1   = (int*)(recip2 + N2);                  // N1
    int*   cnt2   = cnt1 + N1;                            // N2
    int*   off1   = cnt2 + N2;                            // N1+1
    int*   off2   = off1 + N1 + 1;                        // N2+1
    int*   cur1   = off2 + N2 + 1;                        // N1
    int*   cur2   = cur1 + N1;                            // N2
    int*   sorted1= cur2 + N2;                            // E1
    int*   sorted2= sorted1 + E1;                         // E2
    float* outp   = (float*)d_out;                        // N2*D (agg2, then h2 in place)

    // zero only the histograms
    hipMemsetAsync(cnt1, 0, (size_t)(N1 + N2) * sizeof(int), stream);

    int totE = E1 + E2;
    hist_kernel<<<(totE + 255) / 256, 256, 0, stream>>>(dst1, E1, dst2, E2, cnt1, cnt2);
    scan_kernel<<<2, 1024, 0, stream>>>(cnt1, N1, off1, cnt2, N2, off2);
    {
        int totN = N1 + N2;
        prep_kernel<<<(totN + 255) / 256, 256, 0, stream>>>(off1, cnt1, cur1, recip1, N1,
                                                            off2, cnt2, cur2, recip2, N2);
    }
    sort_kernel<<<(totE + 255) / 256, 256, 0, stream>>>(src1, dst1, E1, cur1, sorted1,
                                                        src2, dst2, E2, cur2, sorted2);

    // layer 1: aggregate (gather) + GEMM
    aggregate_kernel<<<(N1 + 3) / 4, 256, 0, stream>>>(nodes, sorted1, off1, recip1, agg1, N1);
    sage_gemm<<<N1 / TM, 256, 0, stream>>>(agg1, nodes, W_l1, b1, W_r1, agg1);

    // layer 2: aggregate (gather) + GEMM
    aggregate_kernel<<<(N2 + 3) / 4, 256, 0, stream>>>(agg1, sorted2, off2, recip2, outp, N2);
    sage_gemm<<<N2 / TM, 256, 0, stream>>>(outp, agg1, W_l2, b2, W_r2, outp);
}

// Round 3
// 632.587 us; speedup vs baseline: 7.3334x; 1.5303x over previous
//
#include <hip/hip_runtime.h>
#include <math.h>

#define D 256
#define KK 512
#define NC1 40   // ceil(40000/1024)
#define NC2 8    // ceil(8000/1024)

typedef __attribute__((ext_vector_type(8))) short short8;
typedef __attribute__((ext_vector_type(4))) float f32x4;

__device__ __forceinline__ unsigned short f2bf(float f) {
    unsigned u = __builtin_bit_cast(unsigned, f);
    u += 0x7fffu + ((u >> 16) & 1u);   // round-to-nearest-even
    return (unsigned short)(u >> 16);
}
__device__ __forceinline__ float bf2f(unsigned short h) {
    unsigned u = ((unsigned)h) << 16;
    return __builtin_bit_cast(float, u);
}
__device__ __forceinline__ float tanh_fast(float x) {
    // tanh(x) = 1 - 2/(exp(2x)+1); exp overflow -> +1, underflow -> -1 (correct limits)
    return 1.0f - 2.0f / (__expf(2.0f * x) + 1.0f);
}

// ---------------- int histogram of dst ----------------
__global__ __launch_bounds__(256) void hist_kernel(const int* __restrict__ dst1, int E1,
                                                   const int* __restrict__ dst2, int E2,
                                                   int* cnt1, int* cnt2) {
    int t = blockIdx.x * 256 + threadIdx.x;
    if (t < E1) {
        atomicAdd(&cnt1[dst1[t]], 1);
    } else if (t < E1 + E2) {
        atomicAdd(&cnt2[dst2[t - E1]], 1);
    }
}

// ---------------- 3-phase exclusive scan ----------------
__global__ __launch_bounds__(256) void scan_phase1(const int* __restrict__ cnt1, int n1, int* off1, int* part1,
                                                   const int* __restrict__ cnt2, int n2, int* off2, int* part2) {
    int b = blockIdx.x;
    const int* cnt; int n; int* off; int* part; int c;
    if (b < NC1) { cnt = cnt1; n = n1; off = off1; part = part1; c = b; }
    else         { cnt = cnt2; n = n2; off = off2; part = part2; c = b - NC1; }
    int t = threadIdx.x;
    int i0 = c * 1024 + t * 4;
    int v[4];
#pragma unroll
    for (int j = 0; j < 4; ++j) v[j] = (i0 + j < n) ? cnt[i0 + j] : 0;
    int s = v[0] + v[1] + v[2] + v[3];
    int lane = t & 63, wid = t >> 6;
    int ps = s;
#pragma unroll
    for (int d = 1; d < 64; d <<= 1) {
        int tmp = __shfl_up(ps, d);
        if (lane >= d) ps += tmp;
    }
    __shared__ int wsum[4];
    if (lane == 63) wsum[wid] = ps;
    __syncthreads();
    int wbase = 0;
    for (int k = 0; k < wid; ++k) wbase += wsum[k];
    int run = wbase + ps - s;   // exclusive prefix for this thread's 4 elems
#pragma unroll
    for (int j = 0; j < 4; ++j) {
        if (i0 + j < n) off[i0 + j] = run;
        run += v[j];
    }
    if (t == 255) part[c] = wbase + ps;   // chunk total
}

__global__ __launch_bounds__(64) void scan_phase2(int* part1, int* part2) {
    if (threadIdx.x == 0) {
        int s = 0;
        for (int i = 0; i < NC1; ++i) { int v = part1[i]; part1[i] = s; s += v; }
        part1[NC1] = s;
    } else if (threadIdx.x == 1) {
        int s = 0;
        for (int i = 0; i < NC2; ++i) { int v = part2[i]; part2[i] = s; s += v; }
        part2[NC2] = s;
    }
}

__global__ __launch_bounds__(256) void scan_phase3(int* off1, int n1, const int* __restrict__ part1,
                                                   int* off2, int n2, const int* __restrict__ part2) {
    int b = blockIdx.x;
    int n; int* off; const int* part; int c;
    if (b < NC1) { n = n1; off = off1; part = part1; c = b; }
    else         { n = n2; off = off2; part = part2; c = b - NC1; }
    int t = threadIdx.x;
    int i0 = c * 1024 + t * 4;
    int add = part[c];
#pragma unroll
    for (int j = 0; j < 4; ++j)
        if (i0 + j < n) off[i0 + j] += add;
    if (b == 0 && t == 0) off1[n1] = part1[NC1];
    if (b == NC1 && t == 0) off2[n2] = part2[NC2];
}

// ---------------- cursors + recip ----------------
__global__ __launch_bounds__(256) void prep_kernel(const int* __restrict__ off1, const int* __restrict__ cnt1,
                                                   int* cur1, float* recip1, int n1,
                                                   const int* __restrict__ off2, const int* __restrict__ cnt2,
                                                   int* cur2, float* recip2, int n2) {
    int t = blockIdx.x * 256 + threadIdx.x;
    if (t < n1) {
        cur1[t] = off1[t];
        recip1[t] = 1.0f / fmaxf((float)cnt1[t], 1.0f);
    } else if (t < n1 + n2) {
        int u = t - n1;
        cur2[u] = off2[u];
        recip2[u] = 1.0f / fmaxf((float)cnt2[u], 1.0f);
    }
}

// ---------------- counting-sort edges by dst ----------------
__global__ __launch_bounds__(256) void sort_kernel(const int* __restrict__ src1, const int* __restrict__ dst1, int E1,
                                                   int* cur1, int* sorted1,
                                                   const int* __restrict__ src2, const int* __restrict__ dst2, int E2,
                                                   int* cur2, int* sorted2) {
    int t = blockIdx.x * 256 + threadIdx.x;
    if (t < E1) {
        int d = dst1[t];
        int p = atomicAdd(&cur1[d], 1);
        sorted1[p] = src1[t];
    } else if (t < E1 + E2) {
        int u = t - E1;
        int d = dst2[u];
        int p = atomicAdd(&cur2[d], 1);
        sorted2[p] = src2[u];
    }
}

// ---------------- weight concat + bf16 convert ----------------
// Wc[n][k] (n=0..255, k=0..511): k<256 -> Wl[n][k], else Wr[n][k-256]
__global__ __launch_bounds__(256) void prep_weights(const float* __restrict__ Wl1, const float* __restrict__ Wr1,
                                                    const float* __restrict__ Wl2, const float* __restrict__ Wr2,
                                                    unsigned short* Wc1, unsigned short* Wc2) {
    int t = blockIdx.x * 256 + threadIdx.x;   // 0 .. 2*131072
    int which = t >> 17;
    int u = t & 131071;
    int nrow = u >> 9;
    int k = u & 511;
    const float* Wl = which ? Wl2 : Wl1;
    const float* Wr = which ? Wr2 : Wr1;
    unsigned short* Wc = which ? Wc2 : Wc1;
    float v = (k < 256) ? Wl[nrow * 256 + k] : Wr[nrow * 256 + (k - 256)];
    Wc[u] = f2bf(v);
}

// ---------------- gather-aggregate (fp32 source) -> bf16 mean ----------------
__global__ __launch_bounds__(256) void aggregate_f32(const float* __restrict__ x,
                                                     const int* __restrict__ sorted,
                                                     const int* __restrict__ off,
                                                     const float* __restrict__ recip,
                                                     unsigned short* __restrict__ mean, int n) {
    int node = blockIdx.x * 4 + (threadIdx.x >> 6);
    if (node >= n) return;
    int l = threadIdx.x & 63;
    int beg = off[node], end = off[node + 1];

    float4 a0 = {0.f, 0.f, 0.f, 0.f};
    float4 a1 = {0.f, 0.f, 0.f, 0.f};
    int e = beg;
    for (; e + 1 < end; e += 2) {
        int s0 = sorted[e];
        int s1 = sorted[e + 1];
        float4 v0 = *(const float4*)(x + (size_t)s0 * D + l * 4);
        float4 v1 = *(const float4*)(x + (size_t)s1 * D + l * 4);
        a0.x += v0.x; a0.y += v0.y; a0.z += v0.z; a0.w += v0.w;
        a1.x += v1.x; a1.y += v1.y; a1.z += v1.z; a1.w += v1.w;
    }
    if (e < end) {
        int s = sorted[e];
        float4 v = *(const float4*)(x + (size_t)s * D + l * 4);
        a0.x += v.x; a0.y += v.y; a0.z += v.z; a0.w += v.w;
    }
    float r = recip[node];
    ushort4 o;
    o.x = f2bf((a0.x + a1.x) * r);
    o.y = f2bf((a0.y + a1.y) * r);
    o.z = f2bf((a0.z + a1.z) * r);
    o.w = f2bf((a0.w + a1.w) * r);
    *(ushort4*)(mean + (size_t)node * D + l * 4) = o;
}

// ---------------- gather-aggregate (bf16 source) -> bf16 mean ----------------
__global__ __launch_bounds__(256) void aggregate_bf16(const unsigned short* __restrict__ x,
                                                      const int* __restrict__ sorted,
                                                      const int* __restrict__ off,
                                                      const float* __restrict__ recip,
                                                      unsigned short* __restrict__ mean, int n) {
    int node = blockIdx.x * 4 + (threadIdx.x >> 6);
    if (node >= n) return;
    int l = threadIdx.x & 63;
    int beg = off[node], end = off[node + 1];

    float a[4] = {0.f, 0.f, 0.f, 0.f};
    for (int e = beg; e < end; ++e) {
        int s = sorted[e];
        ushort4 v = *(const ushort4*)(x + (size_t)s * D + l * 4);
        a[0] += bf2f(v.x); a[1] += bf2f(v.y); a[2] += bf2f(v.z); a[3] += bf2f(v.w);
    }
    float r = recip[node];
    ushort4 o;
    o.x = f2bf(a[0] * r);
    o.y = f2bf(a[1] * r);
    o.z = f2bf(a[2] * r);
    o.w = f2bf(a[3] * r);
    *(ushort4*)(mean + (size_t)node * D + l * 4) = o;
}

// ---------------- bf16 MFMA SAGE GEMM ----------------
// out[m][n] = tanh( sum_{k<512} A'[m][k] * Wcat[n][k] + bias[n] )
// A' = [mean(bf16) | x(fp32 or bf16)]. Tile 128x128, BK=64, 4 waves 2x2,
// each wave 4x4 MFMA 16x16x32 tiles. LDS padded (+8 bf16/row) -> 2-way
// bank aliasing only (free). A-frag: A[m=lane&15][k=quad*8+j]; C/D:
// col=lane&15, row=quad*4+reg (guide §3, m89-verified).
template<bool X_FP32, bool OUT_BF16>
__global__ __launch_bounds__(256) void sage_gemm_mfma(const unsigned short* __restrict__ meanp,
                                                      const void* __restrict__ xp,
                                                      const unsigned short* __restrict__ Wcat,
                                                      const float* __restrict__ bias,
                                                      void* __restrict__ outp,
                                                      int M) {
    __shared__ unsigned short Asb[128 * 72];
    __shared__ unsigned short Wsb[128 * 72];

    const int tid = threadIdx.x;
    const int lane = tid & 63;
    const int w = tid >> 6;
    const int wm = w & 1, wn = w >> 1;
    const int quad = lane >> 4, lr = lane & 15;
    const int row0 = blockIdx.x * 128;
    const int n0 = blockIdx.y * 128;

    f32x4 acc[4][4] = {};

    for (int kt = 0; kt < 8; ++kt) {
        const bool mh = (kt < 4);
        const int kg0 = mh ? kt * 64 : (kt - 4) * 64;

        // ---- stage A tile (128 x 64 bf16) ----
#pragma unroll
        for (int i = 0; i < 4; ++i) {
            int f = i * 256 + tid;
            int r = f >> 3;
            int c8 = (f & 7) * 8;
            int gr = row0 + r;
            unsigned short tmp[8];
            if (gr < M) {
                if (mh) {
                    *(short8*)tmp = *(const short8*)(meanp + (size_t)gr * D + kg0 + c8);
                } else if (X_FP32) {
                    const float* xf = (const float*)xp + (size_t)gr * D + kg0 + c8;
                    float4 v0 = *(const float4*)xf;
                    float4 v1 = *(const float4*)(xf + 4);
                    tmp[0] = f2bf(v0.x); tmp[1] = f2bf(v0.y); tmp[2] = f2bf(v0.z); tmp[3] = f2bf(v0.w);
                    tmp[4] = f2bf(v1.x); tmp[5] = f2bf(v1.y); tmp[6] = f2bf(v1.z); tmp[7] = f2bf(v1.w);
                } else {
                    *(short8*)tmp = *(const short8*)((const unsigned short*)xp + (size_t)gr * D + kg0 + c8);
                }
            } else {
#pragma unroll
                for (int j = 0; j < 8; ++j) tmp[j] = 0;
            }
            *(short8*)&Asb[r * 72 + c8] = *(short8*)tmp;
        }

        // ---- stage W tile (128 x 64 bf16) ----
#pragma unroll
        for (int i = 0; i < 4; ++i) {
            int f = i * 256 + tid;
            int nn = f >> 3;
            int c8 = (f & 7) * 8;
            *(short8*)&Wsb[nn * 72 + c8] =
                *(const short8*)(Wcat + (size_t)(n0 + nn) * KK + kt * 64 + c8);
        }

        __syncthreads();

#pragma unroll
        for (int ks = 0; ks < 64; ks += 32) {
            short8 a[4], b[4];
#pragma unroll
            for (int mt = 0; mt < 4; ++mt)
                a[mt] = *(const short8*)&Asb[(wm * 64 + mt * 16 + lr) * 72 + ks + quad * 8];
#pragma unroll
            for (int nt = 0; nt < 4; ++nt)
                b[nt] = *(const short8*)&Wsb[(wn * 64 + nt * 16 + lr) * 72 + ks + quad * 8];
#pragma unroll
            for (int mt = 0; mt < 4; ++mt)
#pragma unroll
                for (int nt = 0; nt < 4; ++nt)
                    acc[mt][nt] = __builtin_amdgcn_mfma_f32_16x16x32_bf16(a[mt], b[nt], acc[mt][nt], 0, 0, 0);
        }

        __syncthreads();
    }

    // ---- epilogue: bias + tanh + store ----
#pragma unroll
    for (int mt = 0; mt < 4; ++mt) {
        int gr0 = row0 + wm * 64 + mt * 16 + quad * 4;
#pragma unroll
        for (int nt = 0; nt < 4; ++nt) {
            int col = n0 + wn * 64 + nt * 16 + lr;
            float bc = bias[col];
#pragma unroll
            for (int r = 0; r < 4; ++r) {
                int gr = gr0 + r;
                if (gr < M) {
                    float v = tanh_fast(acc[mt][nt][r] + bc);
                    if (OUT_BF16) ((unsigned short*)outp)[(size_t)gr * D + col] = f2bf(v);
                    else          ((float*)outp)[(size_t)gr * D + col] = v;
                }
            }
        }
    }
}

extern "C" void kernel_launch(void* const* d_in, const int* in_sizes, int n_in,
                              void* d_out, int out_size, void* d_ws, size_t ws_size,
                              hipStream_t stream) {
    const float* nodes = (const float*)d_in[0];
    const float* W_l1  = (const float*)d_in[1];
    const float* b1    = (const float*)d_in[2];
    const float* W_r1  = (const float*)d_in[3];
    const float* W_l2  = (const float*)d_in[4];
    const float* b2    = (const float*)d_in[5];
    const float* W_r2  = (const float*)d_in[6];
    const int* src1 = (const int*)d_in[7];
    const int* dst1 = (const int*)d_in[8];
    const int* src2 = (const int*)d_in[9];
    const int* dst2 = (const int*)d_in[10];

    const int E1 = in_sizes[7];
    const int E2 = in_sizes[9];
    const int N1 = 40000;
    const int N2 = 8000;

    // ---- workspace carve (all 256B-aligned) ----
    char* p = (char*)d_ws;
    auto carve = [&](size_t bytes) -> char* {
        char* q = p;
        p += (bytes + 255) & ~(size_t)255;
        return q;
    };
    unsigned short* mean1 = (unsigned short*)carve((size_t)N1 * D * 2);
    unsigned short* h1    = (unsigned short*)carve((size_t)N1 * D * 2);
    unsigned short* mean2 = (unsigned short*)carve((size_t)N2 * D * 2);
    unsigned short* Wc1   = (unsigned short*)carve((size_t)D * KK * 2);
    unsigned short* Wc2   = (unsigned short*)carve((size_t)D * KK * 2);
    float* recip1 = (float*)carve((size_t)N1 * 4);
    float* recip2 = (float*)carve((size_t)N2 * 4);
    int* cnt1 = (int*)carve((size_t)(N1 + N2) * 4);   // cnt1+cnt2 contiguous for one memset
    int* cnt2 = cnt1 + N1;
    int* off1 = (int*)carve((size_t)(N1 + 1) * 4);
    int* off2 = (int*)carve((size_t)(N2 + 1) * 4);
    int* cur1 = (int*)carve((size_t)N1 * 4);
    int* cur2 = (int*)carve((size_t)N2 * 4);
    int* part1 = (int*)carve((size_t)(NC1 + 1) * 4);
    int* part2 = (int*)carve((size_t)(NC2 + 1) * 4);
    int* sorted1 = (int*)carve((size_t)E1 * 4);
    int* sorted2 = (int*)carve((size_t)E2 * 4);

    hipMemsetAsync(cnt1, 0, (size_t)(N1 + N2) * sizeof(int), stream);

    int totE = E1 + E2;
    hist_kernel<<<(totE + 255) / 256, 256, 0, stream>>>(dst1, E1, dst2, E2, cnt1, cnt2);
    scan_phase1<<<NC1 + NC2, 256, 0, stream>>>(cnt1, N1, off1, part1, cnt2, N2, off2, part2);
    scan_phase2<<<1, 64, 0, stream>>>(part1, part2);
    scan_phase3<<<NC1 + NC2, 256, 0, stream>>>(off1, N1, part1, off2, N2, part2);
    {
        int totN = N1 + N2;
        prep_kernel<<<(totN + 255) / 256, 256, 0, stream>>>(off1, cnt1, cur1, recip1, N1,
                                                            off2, cnt2, cur2, recip2, N2);
    }
    sort_kernel<<<(totE + 255) / 256, 256, 0, stream>>>(src1, dst1, E1, cur1, sorted1,
                                                        src2, dst2, E2, cur2, sorted2);
    prep_weights<<<1024, 256, 0, stream>>>(W_l1, W_r1, W_l2, W_r2, Wc1, Wc2);

    // layer 1
    aggregate_f32<<<N1 / 4, 256, 0, stream>>>(nodes, sorted1, off1, recip1, mean1, N1);
    sage_gemm_mfma<true, true><<<dim3((N1 + 127) / 128, 2), 256, 0, stream>>>(
        mean1, (const void*)nodes, Wc1, b1, (void*)h1, N1);

    // layer 2
    aggregate_bf16<<<N2 / 4, 256, 0, stream>>>(h1, sorted2, off2, recip2, mean2, N2);
    sage_gemm_mfma<false, false><<<dim3((N2 + 127) / 128, 2), 256, 0, stream>>>(
        mean2, (const void*)h1, Wc2, b2, d_out, N2);
}

// Round 4
// 616.960 us; speedup vs baseline: 7.5191x; 1.0253x over previous
//
#include <hip/hip_runtime.h>
#include <math.h>

#define D 256
#define KK 512
#define NC1 40   // ceil(40000/1024)
#define NC2 8    // ceil(8000/1024)

typedef __attribute__((ext_vector_type(8))) short short8;
typedef __attribute__((ext_vector_type(4))) float f32x4;

__device__ __forceinline__ unsigned short f2bf(float f) {
    unsigned u = __builtin_bit_cast(unsigned, f);
    u += 0x7fffu + ((u >> 16) & 1u);   // round-to-nearest-even
    return (unsigned short)(u >> 16);
}
__device__ __forceinline__ float bf2f(unsigned short h) {
    unsigned u = ((unsigned)h) << 16;
    return __builtin_bit_cast(float, u);
}
__device__ __forceinline__ float tanh_fast(float x) {
    // tanh(x) = 1 - 2/(exp(2x)+1); exp overflow -> +1, underflow -> -1 (correct limits)
    return 1.0f - 2.0f / (__expf(2.0f * x) + 1.0f);
}

// ---------------- fp32 -> bf16 node conversion ----------------
__global__ __launch_bounds__(256) void convert_nodes(const float* __restrict__ x,
                                                     unsigned short* __restrict__ y, int total8) {
    int t = blockIdx.x * 256 + threadIdx.x;
    if (t >= total8) return;
    const float* xp = x + (size_t)t * 8;
    float4 v0 = *(const float4*)xp;
    float4 v1 = *(const float4*)(xp + 4);
    unsigned short o[8];
    o[0] = f2bf(v0.x); o[1] = f2bf(v0.y); o[2] = f2bf(v0.z); o[3] = f2bf(v0.w);
    o[4] = f2bf(v1.x); o[5] = f2bf(v1.y); o[6] = f2bf(v1.z); o[7] = f2bf(v1.w);
    *(short8*)(y + (size_t)t * 8) = *(short8*)o;
}

// ---------------- int histogram of dst ----------------
__global__ __launch_bounds__(256) void hist_kernel(const int* __restrict__ dst1, int E1,
                                                   const int* __restrict__ dst2, int E2,
                                                   int* cnt1, int* cnt2) {
    int t = blockIdx.x * 256 + threadIdx.x;
    if (t < E1) {
        atomicAdd(&cnt1[dst1[t]], 1);
    } else if (t < E1 + E2) {
        atomicAdd(&cnt2[dst2[t - E1]], 1);
    }
}

// ---------------- 3-phase exclusive scan ----------------
__global__ __launch_bounds__(256) void scan_phase1(const int* __restrict__ cnt1, int n1, int* off1, int* part1,
                                                   const int* __restrict__ cnt2, int n2, int* off2, int* part2) {
    int b = blockIdx.x;
    const int* cnt; int n; int* off; int* part; int c;
    if (b < NC1) { cnt = cnt1; n = n1; off = off1; part = part1; c = b; }
    else         { cnt = cnt2; n = n2; off = off2; part = part2; c = b - NC1; }
    int t = threadIdx.x;
    int i0 = c * 1024 + t * 4;
    int v[4];
#pragma unroll
    for (int j = 0; j < 4; ++j) v[j] = (i0 + j < n) ? cnt[i0 + j] : 0;
    int s = v[0] + v[1] + v[2] + v[3];
    int lane = t & 63, wid = t >> 6;
    int ps = s;
#pragma unroll
    for (int d = 1; d < 64; d <<= 1) {
        int tmp = __shfl_up(ps, d);
        if (lane >= d) ps += tmp;
    }
    __shared__ int wsum[4];
    if (lane == 63) wsum[wid] = ps;
    __syncthreads();
    int wbase = 0;
    for (int k = 0; k < wid; ++k) wbase += wsum[k];
    int run = wbase + ps - s;   // exclusive prefix for this thread's 4 elems
#pragma unroll
    for (int j = 0; j < 4; ++j) {
        if (i0 + j < n) off[i0 + j] = run;
        run += v[j];
    }
    if (t == 255) part[c] = wbase + ps;   // chunk total
}

__global__ __launch_bounds__(64) void scan_phase2(int* part1, int* part2) {
    if (threadIdx.x == 0) {
        int s = 0;
        for (int i = 0; i < NC1; ++i) { int v = part1[i]; part1[i] = s; s += v; }
        part1[NC1] = s;
    } else if (threadIdx.x == 1) {
        int s = 0;
        for (int i = 0; i < NC2; ++i) { int v = part2[i]; part2[i] = s; s += v; }
        part2[NC2] = s;
    }
}

__global__ __launch_bounds__(256) void scan_phase3(int* off1, int n1, const int* __restrict__ part1,
                                                   int* off2, int n2, const int* __restrict__ part2) {
    int b = blockIdx.x;
    int n; int* off; const int* part; int c;
    if (b < NC1) { n = n1; off = off1; part = part1; c = b; }
    else         { n = n2; off = off2; part = part2; c = b - NC1; }
    int t = threadIdx.x;
    int i0 = c * 1024 + t * 4;
    int add = part[c];
#pragma unroll
    for (int j = 0; j < 4; ++j)
        if (i0 + j < n) off[i0 + j] += add;
    if (b == 0 && t == 0) off1[n1] = part1[NC1];
    if (b == NC1 && t == 0) off2[n2] = part2[NC2];
}

// ---------------- cursors + recip ----------------
__global__ __launch_bounds__(256) void prep_kernel(const int* __restrict__ off1, const int* __restrict__ cnt1,
                                                   int* cur1, float* recip1, int n1,
                                                   const int* __restrict__ off2, const int* __restrict__ cnt2,
                                                   int* cur2, float* recip2, int n2) {
    int t = blockIdx.x * 256 + threadIdx.x;
    if (t < n1) {
        cur1[t] = off1[t];
        recip1[t] = 1.0f / fmaxf((float)cnt1[t], 1.0f);
    } else if (t < n1 + n2) {
        int u = t - n1;
        cur2[u] = off2[u];
        recip2[u] = 1.0f / fmaxf((float)cnt2[u], 1.0f);
    }
}

// ---------------- counting-sort edges by dst ----------------
__global__ __launch_bounds__(256) void sort_kernel(const int* __restrict__ src1, const int* __restrict__ dst1, int E1,
                                                   int* cur1, int* sorted1,
                                                   const int* __restrict__ src2, const int* __restrict__ dst2, int E2,
                                                   int* cur2, int* sorted2) {
    int t = blockIdx.x * 256 + threadIdx.x;
    if (t < E1) {
        int d = dst1[t];
        int p = atomicAdd(&cur1[d], 1);
        sorted1[p] = src1[t];
    } else if (t < E1 + E2) {
        int u = t - E1;
        int d = dst2[u];
        int p = atomicAdd(&cur2[d], 1);
        sorted2[p] = src2[u];
    }
}

// ---------------- weight concat + bf16 convert ----------------
__global__ __launch_bounds__(256) void prep_weights(const float* __restrict__ Wl1, const float* __restrict__ Wr1,
                                                    const float* __restrict__ Wl2, const float* __restrict__ Wr2,
                                                    unsigned short* Wc1, unsigned short* Wc2) {
    int t = blockIdx.x * 256 + threadIdx.x;   // 0 .. 2*131072
    int which = t >> 17;
    int u = t & 131071;
    int nrow = u >> 9;
    int k = u & 511;
    const float* Wl = which ? Wl2 : Wl1;
    const float* Wr = which ? Wr2 : Wr1;
    unsigned short* Wc = which ? Wc2 : Wc1;
    float v = (k < 256) ? Wl[nrow * 256 + k] : Wr[nrow * 256 + (k - 256)];
    Wc[u] = f2bf(v);
}

// ---------------- gather-aggregate (fp32 source) -> bf16 mean (fallback) ----------------
__global__ __launch_bounds__(256) void aggregate_f32(const float* __restrict__ x,
                                                     const int* __restrict__ sorted,
                                                     const int* __restrict__ off,
                                                     const float* __restrict__ recip,
                                                     unsigned short* __restrict__ mean, int n) {
    int node = blockIdx.x * 4 + (threadIdx.x >> 6);
    if (node >= n) return;
    int l = threadIdx.x & 63;
    int beg = off[node], end = off[node + 1];

    float4 a0 = {0.f, 0.f, 0.f, 0.f};
    float4 a1 = {0.f, 0.f, 0.f, 0.f};
    int e = beg;
    for (; e + 1 < end; e += 2) {
        int s0 = sorted[e];
        int s1 = sorted[e + 1];
        float4 v0 = *(const float4*)(x + (size_t)s0 * D + l * 4);
        float4 v1 = *(const float4*)(x + (size_t)s1 * D + l * 4);
        a0.x += v0.x; a0.y += v0.y; a0.z += v0.z; a0.w += v0.w;
        a1.x += v1.x; a1.y += v1.y; a1.z += v1.z; a1.w += v1.w;
    }
    if (e < end) {
        int s = sorted[e];
        float4 v = *(const float4*)(x + (size_t)s * D + l * 4);
        a0.x += v.x; a0.y += v.y; a0.z += v.z; a0.w += v.w;
    }
    float r = recip[node];
    ushort4 o;
    o.x = f2bf((a0.x + a1.x) * r);
    o.y = f2bf((a0.y + a1.y) * r);
    o.z = f2bf((a0.z + a1.z) * r);
    o.w = f2bf((a0.w + a1.w) * r);
    *(ushort4*)(mean + (size_t)node * D + l * 4) = o;
}

// ---------------- gather-aggregate (bf16 source) -> bf16 mean ----------------
// one wave per node; lane l holds dims [4l,4l+4); 4-edge unroll for MLP.
__global__ __launch_bounds__(256) void aggregate_bf16(const unsigned short* __restrict__ x,
                                                      const int* __restrict__ sorted,
                                                      const int* __restrict__ off,
                                                      const float* __restrict__ recip,
                                                      unsigned short* __restrict__ mean, int n) {
    int node = blockIdx.x * 4 + (threadIdx.x >> 6);
    if (node >= n) return;
    int l = threadIdx.x & 63;
    int beg = off[node], end = off[node + 1];

    float a0[4] = {0.f, 0.f, 0.f, 0.f};
    float a1[4] = {0.f, 0.f, 0.f, 0.f};
    float a2[4] = {0.f, 0.f, 0.f, 0.f};
    float a3[4] = {0.f, 0.f, 0.f, 0.f};
    int e = beg;
    for (; e + 3 < end; e += 4) {
        int s0 = sorted[e], s1 = sorted[e + 1], s2 = sorted[e + 2], s3 = sorted[e + 3];
        ushort4 v0 = *(const ushort4*)(x + (size_t)s0 * D + l * 4);
        ushort4 v1 = *(const ushort4*)(x + (size_t)s1 * D + l * 4);
        ushort4 v2 = *(const ushort4*)(x + (size_t)s2 * D + l * 4);
        ushort4 v3 = *(const ushort4*)(x + (size_t)s3 * D + l * 4);
        a0[0] += bf2f(v0.x); a0[1] += bf2f(v0.y); a0[2] += bf2f(v0.z); a0[3] += bf2f(v0.w);
        a1[0] += bf2f(v1.x); a1[1] += bf2f(v1.y); a1[2] += bf2f(v1.z); a1[3] += bf2f(v1.w);
        a2[0] += bf2f(v2.x); a2[1] += bf2f(v2.y); a2[2] += bf2f(v2.z); a2[3] += bf2f(v2.w);
        a3[0] += bf2f(v3.x); a3[1] += bf2f(v3.y); a3[2] += bf2f(v3.z); a3[3] += bf2f(v3.w);
    }
    for (; e < end; ++e) {
        int s = sorted[e];
        ushort4 v = *(const ushort4*)(x + (size_t)s * D + l * 4);
        a0[0] += bf2f(v.x); a0[1] += bf2f(v.y); a0[2] += bf2f(v.z); a0[3] += bf2f(v.w);
    }
    float r = recip[node];
    ushort4 o;
    o.x = f2bf((a0[0] + a1[0] + a2[0] + a3[0]) * r);
    o.y = f2bf((a0[1] + a1[1] + a2[1] + a3[1]) * r);
    o.z = f2bf((a0[2] + a1[2] + a2[2] + a3[2]) * r);
    o.w = f2bf((a0[3] + a1[3] + a2[3] + a3[3]) * r);
    *(ushort4*)(mean + (size_t)node * D + l * 4) = o;
}

// ---------------- bf16 MFMA SAGE GEMM ----------------
// out[m][n] = tanh( sum_{k<512} A'[m][k] * Wcat[n][k] + bias[n] )
// A' = [mean(bf16) | x(fp32 or bf16)]. Tile 128x128, BK=64, 4 waves 2x2,
// each wave 4x4 MFMA 16x16x32 tiles. LDS padded (+8 bf16/row).
template<bool X_FP32, bool OUT_BF16>
__global__ __launch_bounds__(256) void sage_gemm_mfma(const unsigned short* __restrict__ meanp,
                                                      const void* __restrict__ xp,
                                                      const unsigned short* __restrict__ Wcat,
                                                      const float* __restrict__ bias,
                                                      void* __restrict__ outp,
                                                      int M) {
    __shared__ unsigned short Asb[128 * 72];
    __shared__ unsigned short Wsb[128 * 72];

    const int tid = threadIdx.x;
    const int lane = tid & 63;
    const int w = tid >> 6;
    const int wm = w & 1, wn = w >> 1;
    const int quad = lane >> 4, lr = lane & 15;
    const int row0 = blockIdx.x * 128;
    const int n0 = blockIdx.y * 128;

    f32x4 acc[4][4] = {};

    for (int kt = 0; kt < 8; ++kt) {
        const bool mh = (kt < 4);
        const int kg0 = mh ? kt * 64 : (kt - 4) * 64;

        // ---- stage A tile (128 x 64 bf16) ----
#pragma unroll
        for (int i = 0; i < 4; ++i) {
            int f = i * 256 + tid;
            int r = f >> 3;
            int c8 = (f & 7) * 8;
            int gr = row0 + r;
            unsigned short tmp[8];
            if (gr < M) {
                if (mh) {
                    *(short8*)tmp = *(const short8*)(meanp + (size_t)gr * D + kg0 + c8);
                } else if (X_FP32) {
                    const float* xf = (const float*)xp + (size_t)gr * D + kg0 + c8;
                    float4 v0 = *(const float4*)xf;
                    float4 v1 = *(const float4*)(xf + 4);
                    tmp[0] = f2bf(v0.x); tmp[1] = f2bf(v0.y); tmp[2] = f2bf(v0.z); tmp[3] = f2bf(v0.w);
                    tmp[4] = f2bf(v1.x); tmp[5] = f2bf(v1.y); tmp[6] = f2bf(v1.z); tmp[7] = f2bf(v1.w);
                } else {
                    *(short8*)tmp = *(const short8*)((const unsigned short*)xp + (size_t)gr * D + kg0 + c8);
                }
            } else {
#pragma unroll
                for (int j = 0; j < 8; ++j) tmp[j] = 0;
            }
            *(short8*)&Asb[r * 72 + c8] = *(short8*)tmp;
        }

        // ---- stage W tile (128 x 64 bf16) ----
#pragma unroll
        for (int i = 0; i < 4; ++i) {
            int f = i * 256 + tid;
            int nn = f >> 3;
            int c8 = (f & 7) * 8;
            *(short8*)&Wsb[nn * 72 + c8] =
                *(const short8*)(Wcat + (size_t)(n0 + nn) * KK + kt * 64 + c8);
        }

        __syncthreads();

#pragma unroll
        for (int ks = 0; ks < 64; ks += 32) {
            short8 a[4], b[4];
#pragma unroll
            for (int mt = 0; mt < 4; ++mt)
                a[mt] = *(const short8*)&Asb[(wm * 64 + mt * 16 + lr) * 72 + ks + quad * 8];
#pragma unroll
            for (int nt = 0; nt < 4; ++nt)
                b[nt] = *(const short8*)&Wsb[(wn * 64 + nt * 16 + lr) * 72 + ks + quad * 8];
#pragma unroll
            for (int mt = 0; mt < 4; ++mt)
#pragma unroll
                for (int nt = 0; nt < 4; ++nt)
                    acc[mt][nt] = __builtin_amdgcn_mfma_f32_16x16x32_bf16(a[mt], b[nt], acc[mt][nt], 0, 0, 0);
        }

        __syncthreads();
    }

    // ---- epilogue: bias + tanh + store ----
#pragma unroll
    for (int mt = 0; mt < 4; ++mt) {
        int gr0 = row0 + wm * 64 + mt * 16 + quad * 4;
#pragma unroll
        for (int nt = 0; nt < 4; ++nt) {
            int col = n0 + wn * 64 + nt * 16 + lr;
            float bc = bias[col];
#pragma unroll
            for (int r = 0; r < 4; ++r) {
                int gr = gr0 + r;
                if (gr < M) {
                    float v = tanh_fast(acc[mt][nt][r] + bc);
                    if (OUT_BF16) ((unsigned short*)outp)[(size_t)gr * D + col] = f2bf(v);
                    else          ((float*)outp)[(size_t)gr * D + col] = v;
                }
            }
        }
    }
}

extern "C" void kernel_launch(void* const* d_in, const int* in_sizes, int n_in,
                              void* d_out, int out_size, void* d_ws, size_t ws_size,
                              hipStream_t stream) {
    const float* nodes = (const float*)d_in[0];
    const float* W_l1  = (const float*)d_in[1];
    const float* b1    = (const float*)d_in[2];
    const float* W_r1  = (const float*)d_in[3];
    const float* W_l2  = (const float*)d_in[4];
    const float* b2    = (const float*)d_in[5];
    const float* W_r2  = (const float*)d_in[6];
    const int* src1 = (const int*)d_in[7];
    const int* dst1 = (const int*)d_in[8];
    const int* src2 = (const int*)d_in[9];
    const int* dst2 = (const int*)d_in[10];

    const int E1 = in_sizes[7];
    const int E2 = in_sizes[9];
    const int N0 = in_sizes[0] / D;   // 200000
    const int N1 = 40000;
    const int N2 = 8000;

    // ---- workspace carve (all 256B-aligned) ----
    char* p = (char*)d_ws;
    auto carve = [&](size_t bytes) -> char* {
        char* q = p;
        p += (bytes + 255) & ~(size_t)255;
        return q;
    };
    unsigned short* mean1 = (unsigned short*)carve((size_t)N1 * D * 2);
    unsigned short* h1    = (unsigned short*)carve((size_t)N1 * D * 2);
    unsigned short* mean2 = (unsigned short*)carve((size_t)N2 * D * 2);
    unsigned short* Wc1   = (unsigned short*)carve((size_t)D * KK * 2);
    unsigned short* Wc2   = (unsigned short*)carve((size_t)D * KK * 2);
    float* recip1 = (float*)carve((size_t)N1 * 4);
    float* recip2 = (float*)carve((size_t)N2 * 4);
    int* cnt1 = (int*)carve((size_t)(N1 + N2) * 4);
    int* cnt2 = cnt1 + N1;
    int* off1 = (int*)carve((size_t)(N1 + 1) * 4);
    int* off2 = (int*)carve((size_t)(N2 + 1) * 4);
    int* cur1 = (int*)carve((size_t)N1 * 4);
    int* cur2 = (int*)carve((size_t)N2 * 4);
    int* part1 = (int*)carve((size_t)(NC1 + 1) * 4);
    int* part2 = (int*)carve((size_t)(NC2 + 1) * 4);
    int* sorted1 = (int*)carve((size_t)E1 * 4);
    int* sorted2 = (int*)carve((size_t)E2 * 4);
    unsigned short* nodes_bf = (unsigned short*)carve((size_t)N0 * D * 2);
    const bool use_bf = ((size_t)(p - (char*)d_ws) <= ws_size);   // deterministic; graph-safe

    hipMemsetAsync(cnt1, 0, (size_t)(N1 + N2) * sizeof(int), stream);

    int totE = E1 + E2;
    hist_kernel<<<(totE + 255) / 256, 256, 0, stream>>>(dst1, E1, dst2, E2, cnt1, cnt2);
    scan_phase1<<<NC1 + NC2, 256, 0, stream>>>(cnt1, N1, off1, part1, cnt2, N2, off2, part2);
    scan_phase2<<<1, 64, 0, stream>>>(part1, part2);
    scan_phase3<<<NC1 + NC2, 256, 0, stream>>>(off1, N1, part1, off2, N2, part2);
    {
        int totN = N1 + N2;
        prep_kernel<<<(totN + 255) / 256, 256, 0, stream>>>(off1, cnt1, cur1, recip1, N1,
                                                            off2, cnt2, cur2, recip2, N2);
    }
    sort_kernel<<<(totE + 255) / 256, 256, 0, stream>>>(src1, dst1, E1, cur1, sorted1,
                                                        src2, dst2, E2, cur2, sorted2);
    prep_weights<<<1024, 256, 0, stream>>>(W_l1, W_r1, W_l2, W_r2, Wc1, Wc2);

    if (use_bf) {
        int total8 = N0 * D / 8;
        convert_nodes<<<(total8 + 255) / 256, 256, 0, stream>>>(nodes, nodes_bf, total8);

        // layer 1
        aggregate_bf16<<<N1 / 4, 256, 0, stream>>>(nodes_bf, sorted1, off1, recip1, mean1, N1);
        sage_gemm_mfma<false, true><<<dim3((N1 + 127) / 128, 2), 256, 0, stream>>>(
            mean1, (const void*)nodes_bf, Wc1, b1, (void*)h1, N1);
    } else {
        aggregate_f32<<<N1 / 4, 256, 0, stream>>>(nodes, sorted1, off1, recip1, mean1, N1);
        sage_gemm_mfma<true, true><<<dim3((N1 + 127) / 128, 2), 256, 0, stream>>>(
            mean1, (const void*)nodes, Wc1, b1, (void*)h1, N1);
    }

    // layer 2
    aggregate_bf16<<<N2 / 4, 256, 0, stream>>>(h1, sorted2, off2, recip2, mean2, N2);
    sage_gemm_mfma<false, false><<<dim3((N2 + 127) / 128, 2), 256, 0, stream>>>(
        mean2, (const void*)h1, Wc2, b2, d_out, N2);
}

// Round 5
// 598.304 us; speedup vs baseline: 7.7536x; 1.0312x over previous
//
#include <hip/hip_runtime.h>
#include <math.h>

#define D 256
#define KK 512
#define NC1 40   // ceil(40000/1024)
#define NC2 8    // ceil(8000/1024)

typedef __attribute__((ext_vector_type(8))) short short8;
typedef __attribute__((ext_vector_type(4))) float f32x4;

__device__ __forceinline__ unsigned short f2bf(float f) {
    unsigned u = __builtin_bit_cast(unsigned, f);
    u += 0x7fffu + ((u >> 16) & 1u);   // round-to-nearest-even
    return (unsigned short)(u >> 16);
}
__device__ __forceinline__ float bf2f(unsigned short h) {
    unsigned u = ((unsigned)h) << 16;
    return __builtin_bit_cast(float, u);
}
__device__ __forceinline__ float tanh_fast(float x) {
    return 1.0f - 2.0f / (__expf(2.0f * x) + 1.0f);
}

// ---------------- fused prologue: node bf16 convert + dst histogram + weight prep ----------------
// three independent jobs packed into one launch so they overlap.
__global__ __launch_bounds__(256) void prologue(const float* __restrict__ nodes,
                                                unsigned short* __restrict__ nodes_bf, int total8, int CB,
                                                const int* __restrict__ dst1, int E1,
                                                const int* __restrict__ dst2, int E2,
                                                int* cnt1, int* cnt2, int HB,
                                                const float* __restrict__ Wl1, const float* __restrict__ Wr1,
                                                const float* __restrict__ Wl2, const float* __restrict__ Wr2,
                                                unsigned short* Wc1, unsigned short* Wc2) {
    int b = blockIdx.x;
    if (b < CB) {
        int t = b * 256 + threadIdx.x;
        if (t < total8) {
            const float* xp = nodes + (size_t)t * 8;
            float4 v0 = *(const float4*)xp;
            float4 v1 = *(const float4*)(xp + 4);
            unsigned short o[8];
            o[0] = f2bf(v0.x); o[1] = f2bf(v0.y); o[2] = f2bf(v0.z); o[3] = f2bf(v0.w);
            o[4] = f2bf(v1.x); o[5] = f2bf(v1.y); o[6] = f2bf(v1.z); o[7] = f2bf(v1.w);
            *(short8*)(nodes_bf + (size_t)t * 8) = *(short8*)o;
        }
    } else if (b < CB + HB) {
        int t = (b - CB) * 256 + threadIdx.x;
        if (t < E1) {
            atomicAdd(&cnt1[dst1[t]], 1);
        } else if (t < E1 + E2) {
            atomicAdd(&cnt2[dst2[t - E1]], 1);
        }
    } else {
        int t = (b - CB - HB) * 256 + threadIdx.x;   // 0 .. 2*131072
        int which = t >> 17;
        int u = t & 131071;
        int nrow = u >> 9;
        int k = u & 511;
        const float* Wl = which ? Wl2 : Wl1;
        const float* Wr = which ? Wr2 : Wr1;
        unsigned short* Wc = which ? Wc2 : Wc1;
        float v = (k < 256) ? Wl[nrow * 256 + k] : Wr[nrow * 256 + (k - 256)];
        Wc[u] = f2bf(v);
    }
}

// ---------------- 3-phase exclusive scan ----------------
__global__ __launch_bounds__(256) void scan_phase1(const int* __restrict__ cnt1, int n1, int* off1, int* part1,
                                                   const int* __restrict__ cnt2, int n2, int* off2, int* part2) {
    int b = blockIdx.x;
    const int* cnt; int n; int* off; int* part; int c;
    if (b < NC1) { cnt = cnt1; n = n1; off = off1; part = part1; c = b; }
    else         { cnt = cnt2; n = n2; off = off2; part = part2; c = b - NC1; }
    int t = threadIdx.x;
    int i0 = c * 1024 + t * 4;
    int v[4];
#pragma unroll
    for (int j = 0; j < 4; ++j) v[j] = (i0 + j < n) ? cnt[i0 + j] : 0;
    int s = v[0] + v[1] + v[2] + v[3];
    int lane = t & 63, wid = t >> 6;
    int ps = s;
#pragma unroll
    for (int d = 1; d < 64; d <<= 1) {
        int tmp = __shfl_up(ps, d);
        if (lane >= d) ps += tmp;
    }
    __shared__ int wsum[4];
    if (lane == 63) wsum[wid] = ps;
    __syncthreads();
    int wbase = 0;
    for (int k = 0; k < wid; ++k) wbase += wsum[k];
    int run = wbase + ps - s;
#pragma unroll
    for (int j = 0; j < 4; ++j) {
        if (i0 + j < n) off[i0 + j] = run;
        run += v[j];
    }
    if (t == 255) part[c] = wbase + ps;
}

__global__ __launch_bounds__(64) void scan_phase2(int* part1, int* part2) {
    if (threadIdx.x == 0) {
        int s = 0;
        for (int i = 0; i < NC1; ++i) { int v = part1[i]; part1[i] = s; s += v; }
        part1[NC1] = s;
    } else if (threadIdx.x == 1) {
        int s = 0;
        for (int i = 0; i < NC2; ++i) { int v = part2[i]; part2[i] = s; s += v; }
        part2[NC2] = s;
    }
}

// phase3 + cursor/recip prep fused (off final value computed in-thread)
__global__ __launch_bounds__(256) void scan_phase3_prep(int* off1, const int* __restrict__ cnt1,
                                                        int* cur1, float* recip1, int n1, const int* __restrict__ part1,
                                                        int* off2, const int* __restrict__ cnt2,
                                                        int* cur2, float* recip2, int n2, const int* __restrict__ part2) {
    int b = blockIdx.x;
    int n; int* off; const int* part; const int* cnt; int* cur; float* recip; int c;
    if (b < NC1) { n = n1; off = off1; part = part1; cnt = cnt1; cur = cur1; recip = recip1; c = b; }
    else         { n = n2; off = off2; part = part2; cnt = cnt2; cur = cur2; recip = recip2; c = b - NC1; }
    int t = threadIdx.x;
    int i0 = c * 1024 + t * 4;
    int add = part[c];
#pragma unroll
    for (int j = 0; j < 4; ++j) {
        int i = i0 + j;
        if (i < n) {
            int v = off[i] + add;
            off[i] = v;
            cur[i] = v;
            recip[i] = 1.0f / fmaxf((float)cnt[i], 1.0f);
        }
    }
    if (b == 0 && t == 0) off1[n1] = part1[NC1];
    if (b == NC1 && t == 0) off2[n2] = part2[NC2];
}

// ---------------- counting-sort edges by dst ----------------
__global__ __launch_bounds__(256) void sort_kernel(const int* __restrict__ src1, const int* __restrict__ dst1, int E1,
                                                   int* cur1, int* sorted1,
                                                   const int* __restrict__ src2, const int* __restrict__ dst2, int E2,
                                                   int* cur2, int* sorted2) {
    int t = blockIdx.x * 256 + threadIdx.x;
    if (t < E1) {
        int d = dst1[t];
        int p = atomicAdd(&cur1[d], 1);
        sorted1[p] = src1[t];
    } else if (t < E1 + E2) {
        int u = t - E1;
        int d = dst2[u];
        int p = atomicAdd(&cur2[d], 1);
        sorted2[p] = src2[u];
    }
}

// ---------------- gather-aggregate (fp32 source) -> bf16 mean (fallback only) ----------------
__global__ __launch_bounds__(256) void aggregate_f32(const float* __restrict__ x,
                                                     const int* __restrict__ sorted,
                                                     const int* __restrict__ off,
                                                     const float* __restrict__ recip,
                                                     unsigned short* __restrict__ mean, int n) {
    int node = blockIdx.x * 4 + (threadIdx.x >> 6);
    if (node >= n) return;
    int l = threadIdx.x & 63;
    int beg = off[node], end = off[node + 1];

    float4 a0 = {0.f, 0.f, 0.f, 0.f};
    float4 a1 = {0.f, 0.f, 0.f, 0.f};
    int e = beg;
    for (; e + 1 < end; e += 2) {
        int s0 = sorted[e];
        int s1 = sorted[e + 1];
        float4 v0 = *(const float4*)(x + (size_t)s0 * D + l * 4);
        float4 v1 = *(const float4*)(x + (size_t)s1 * D + l * 4);
        a0.x += v0.x; a0.y += v0.y; a0.z += v0.z; a0.w += v0.w;
        a1.x += v1.x; a1.y += v1.y; a1.z += v1.z; a1.w += v1.w;
    }
    if (e < end) {
        int s = sorted[e];
        float4 v = *(const float4*)(x + (size_t)s * D + l * 4);
        a0.x += v.x; a0.y += v.y; a0.z += v.z; a0.w += v.w;
    }
    float r = recip[node];
    ushort4 o;
    o.x = f2bf((a0.x + a1.x) * r);
    o.y = f2bf((a0.y + a1.y) * r);
    o.z = f2bf((a0.z + a1.z) * r);
    o.w = f2bf((a0.w + a1.w) * r);
    *(ushort4*)(mean + (size_t)node * D + l * 4) = o;
}

// ---------------- gather-aggregate (bf16 source) -> bf16 mean ----------------
// half-wave per edge row: 32 lanes x 16B (dwordx4 sweet spot) = 512B row.
// wave covers 2 edges per load instruction; 4-pair unroll -> 8 edges in flight.
// cross-slot reduce via one shfl_xor(32) per float at the end.
__global__ __launch_bounds__(256) void aggregate_bf16(const unsigned short* __restrict__ x,
                                                      const int* __restrict__ sorted,
                                                      const int* __restrict__ off,
                                                      const float* __restrict__ recip,
                                                      unsigned short* __restrict__ mean, int n) {
    int node = blockIdx.x * 4 + (threadIdx.x >> 6);
    if (node >= n) return;
    int l = threadIdx.x & 63;
    int slot = l >> 5;           // which edge of the pair
    int li = l & 31;             // dims [li*8, li*8+8)
    int beg = off[node], end = off[node + 1];

    float a0[8] = {}, a1[8] = {}, a2[8] = {}, a3[8] = {};
    int e = beg;
    for (; e + 7 < end; e += 8) {
        int s0 = sorted[e + slot];
        int s1 = sorted[e + 2 + slot];
        int s2 = sorted[e + 4 + slot];
        int s3 = sorted[e + 6 + slot];
        short8 v0 = *(const short8*)(x + (size_t)s0 * D + li * 8);
        short8 v1 = *(const short8*)(x + (size_t)s1 * D + li * 8);
        short8 v2 = *(const short8*)(x + (size_t)s2 * D + li * 8);
        short8 v3 = *(const short8*)(x + (size_t)s3 * D + li * 8);
#pragma unroll
        for (int k = 0; k < 8; ++k) {
            a0[k] += bf2f((unsigned short)v0[k]);
            a1[k] += bf2f((unsigned short)v1[k]);
            a2[k] += bf2f((unsigned short)v2[k]);
            a3[k] += bf2f((unsigned short)v3[k]);
        }
    }
    for (; e < end; e += 2) {
        int me = e + slot;
        if (me < end) {
            int s = sorted[me];
            short8 v = *(const short8*)(x + (size_t)s * D + li * 8);
#pragma unroll
            for (int k = 0; k < 8; ++k) a0[k] += bf2f((unsigned short)v[k]);
        }
    }
    float r = recip[node];
    unsigned short o[8];
#pragma unroll
    for (int k = 0; k < 8; ++k) {
        float t = a0[k] + a1[k] + a2[k] + a3[k];
        t += __shfl_xor(t, 32);
        o[k] = f2bf(t * r);
    }
    if (slot == 0)
        *(short8*)(mean + (size_t)node * D + li * 8) = *(short8*)o;
}

// ---------------- bf16 MFMA SAGE GEMM ----------------
// out[m][n] = tanh( sum_{k<512} A'[m][k] * Wcat[n][k] + bias[n] )
// A' = [mean(bf16) | x(fp32 or bf16)]. Tile 128x128, BK=64, 4 waves 2x2,
// each wave 4x4 MFMA 16x16x32 tiles. LDS padded (+8 bf16/row).
template<bool X_FP32, bool OUT_BF16>
__global__ __launch_bounds__(256) void sage_gemm_mfma(const unsigned short* __restrict__ meanp,
                                                      const void* __restrict__ xp,
                                                      const unsigned short* __restrict__ Wcat,
                                                      const float* __restrict__ bias,
                                                      void* __restrict__ outp,
                                                      int M) {
    __shared__ unsigned short Asb[128 * 72];
    __shared__ unsigned short Wsb[128 * 72];

    const int tid = threadIdx.x;
    const int lane = tid & 63;
    const int w = tid >> 6;
    const int wm = w & 1, wn = w >> 1;
    const int quad = lane >> 4, lr = lane & 15;
    const int row0 = blockIdx.x * 128;
    const int n0 = blockIdx.y * 128;

    f32x4 acc[4][4] = {};

    for (int kt = 0; kt < 8; ++kt) {
        const bool mh = (kt < 4);
        const int kg0 = mh ? kt * 64 : (kt - 4) * 64;

#pragma unroll
        for (int i = 0; i < 4; ++i) {
            int f = i * 256 + tid;
            int r = f >> 3;
            int c8 = (f & 7) * 8;
            int gr = row0 + r;
            unsigned short tmp[8];
            if (gr < M) {
                if (mh) {
                    *(short8*)tmp = *(const short8*)(meanp + (size_t)gr * D + kg0 + c8);
                } else if (X_FP32) {
                    const float* xf = (const float*)xp + (size_t)gr * D + kg0 + c8;
                    float4 v0 = *(const float4*)xf;
                    float4 v1 = *(const float4*)(xf + 4);
                    tmp[0] = f2bf(v0.x); tmp[1] = f2bf(v0.y); tmp[2] = f2bf(v0.z); tmp[3] = f2bf(v0.w);
                    tmp[4] = f2bf(v1.x); tmp[5] = f2bf(v1.y); tmp[6] = f2bf(v1.z); tmp[7] = f2bf(v1.w);
                } else {
                    *(short8*)tmp = *(const short8*)((const unsigned short*)xp + (size_t)gr * D + kg0 + c8);
                }
            } else {
#pragma unroll
                for (int j = 0; j < 8; ++j) tmp[j] = 0;
            }
            *(short8*)&Asb[r * 72 + c8] = *(short8*)tmp;
        }

#pragma unroll
        for (int i = 0; i < 4; ++i) {
            int f = i * 256 + tid;
            int nn = f >> 3;
            int c8 = (f & 7) * 8;
            *(short8*)&Wsb[nn * 72 + c8] =
                *(const short8*)(Wcat + (size_t)(n0 + nn) * KK + kt * 64 + c8);
        }

        __syncthreads();

#pragma unroll
        for (int ks = 0; ks < 64; ks += 32) {
            short8 a[4], b[4];
#pragma unroll
            for (int mt = 0; mt < 4; ++mt)
                a[mt] = *(const short8*)&Asb[(wm * 64 + mt * 16 + lr) * 72 + ks + quad * 8];
#pragma unroll
            for (int nt = 0; nt < 4; ++nt)
                b[nt] = *(const short8*)&Wsb[(wn * 64 + nt * 16 + lr) * 72 + ks + quad * 8];
#pragma unroll
            for (int mt = 0; mt < 4; ++mt)
#pragma unroll
                for (int nt = 0; nt < 4; ++nt)
                    acc[mt][nt] = __builtin_amdgcn_mfma_f32_16x16x32_bf16(a[mt], b[nt], acc[mt][nt], 0, 0, 0);
        }

        __syncthreads();
    }

#pragma unroll
    for (int mt = 0; mt < 4; ++mt) {
        int gr0 = row0 + wm * 64 + mt * 16 + quad * 4;
#pragma unroll
        for (int nt = 0; nt < 4; ++nt) {
            int col = n0 + wn * 64 + nt * 16 + lr;
            float bc = bias[col];
#pragma unroll
            for (int r = 0; r < 4; ++r) {
                int gr = gr0 + r;
                if (gr < M) {
                    float v = tanh_fast(acc[mt][nt][r] + bc);
                    if (OUT_BF16) ((unsigned short*)outp)[(size_t)gr * D + col] = f2bf(v);
                    else          ((float*)outp)[(size_t)gr * D + col] = v;
                }
            }
        }
    }
}

extern "C" void kernel_launch(void* const* d_in, const int* in_sizes, int n_in,
                              void* d_out, int out_size, void* d_ws, size_t ws_size,
                              hipStream_t stream) {
    const float* nodes = (const float*)d_in[0];
    const float* W_l1  = (const float*)d_in[1];
    const float* b1    = (const float*)d_in[2];
    const float* W_r1  = (const float*)d_in[3];
    const float* W_l2  = (const float*)d_in[4];
    const float* b2    = (const float*)d_in[5];
    const float* W_r2  = (const float*)d_in[6];
    const int* src1 = (const int*)d_in[7];
    const int* dst1 = (const int*)d_in[8];
    const int* src2 = (const int*)d_in[9];
    const int* dst2 = (const int*)d_in[10];

    const int E1 = in_sizes[7];
    const int E2 = in_sizes[9];
    const int N0 = in_sizes[0] / D;   // 200000
    const int N1 = 40000;
    const int N2 = 8000;

    // ---- workspace carve (256B-aligned) ----
    char* p = (char*)d_ws;
    auto carve = [&](size_t bytes) -> char* {
        char* q = p;
        p += (bytes + 255) & ~(size_t)255;
        return q;
    };
    unsigned short* mean1 = (unsigned short*)carve((size_t)N1 * D * 2);
    unsigned short* h1    = (unsigned short*)carve((size_t)N1 * D * 2);
    unsigned short* mean2 = (unsigned short*)carve((size_t)N2 * D * 2);
    unsigned short* Wc1   = (unsigned short*)carve((size_t)D * KK * 2);
    unsigned short* Wc2   = (unsigned short*)carve((size_t)D * KK * 2);
    float* recip1 = (float*)carve((size_t)N1 * 4);
    float* recip2 = (float*)carve((size_t)N2 * 4);
    int* cnt1 = (int*)carve((size_t)(N1 + N2) * 4);
    int* cnt2 = cnt1 + N1;
    int* off1 = (int*)carve((size_t)(N1 + 1) * 4);
    int* off2 = (int*)carve((size_t)(N2 + 1) * 4);
    int* cur1 = (int*)carve((size_t)N1 * 4);
    int* cur2 = (int*)carve((size_t)N2 * 4);
    int* part1 = (int*)carve((size_t)(NC1 + 1) * 4);
    int* part2 = (int*)carve((size_t)(NC2 + 1) * 4);
    int* sorted1 = (int*)carve((size_t)E1 * 4);
    int* sorted2 = (int*)carve((size_t)E2 * 4);
    unsigned short* nodes_bf = (unsigned short*)carve((size_t)N0 * D * 2);
    const bool use_bf = ((size_t)(p - (char*)d_ws) <= ws_size);   // deterministic; graph-safe

    hipMemsetAsync(cnt1, 0, (size_t)(N1 + N2) * sizeof(int), stream);

    const int totE = E1 + E2;
    const int total8 = N0 * D / 8;
    const int CB = use_bf ? (total8 + 255) / 256 : 0;
    const int HB = (totE + 255) / 256;
    const int WB = (2 * D * KK + 255) / 256;

    prologue<<<CB + HB + WB, 256, 0, stream>>>(nodes, nodes_bf, total8, CB,
                                               dst1, E1, dst2, E2, cnt1, cnt2, HB,
                                               W_l1, W_r1, W_l2, W_r2, Wc1, Wc2);
    scan_phase1<<<NC1 + NC2, 256, 0, stream>>>(cnt1, N1, off1, part1, cnt2, N2, off2, part2);
    scan_phase2<<<1, 64, 0, stream>>>(part1, part2);
    scan_phase3_prep<<<NC1 + NC2, 256, 0, stream>>>(off1, cnt1, cur1, recip1, N1, part1,
                                                    off2, cnt2, cur2, recip2, N2, part2);
    sort_kernel<<<(totE + 255) / 256, 256, 0, stream>>>(src1, dst1, E1, cur1, sorted1,
                                                        src2, dst2, E2, cur2, sorted2);

    if (use_bf) {
        aggregate_bf16<<<N1 / 4, 256, 0, stream>>>(nodes_bf, sorted1, off1, recip1, mean1, N1);
        sage_gemm_mfma<false, true><<<dim3((N1 + 127) / 128, 2), 256, 0, stream>>>(
            mean1, (const void*)nodes_bf, Wc1, b1, (void*)h1, N1);
    } else {
        aggregate_f32<<<N1 / 4, 256, 0, stream>>>(nodes, sorted1, off1, recip1, mean1, N1);
        sage_gemm_mfma<true, true><<<dim3((N1 + 127) / 128, 2), 256, 0, stream>>>(
            mean1, (const void*)nodes, Wc1, b1, (void*)h1, N1);
    }

    // layer 2
    aggregate_bf16<<<N2 / 4, 256, 0, stream>>>(h1, sorted2, off2, recip2, mean2, N2);
    sage_gemm_mfma<false, false><<<dim3((N2 + 127) / 128, 2), 256, 0, stream>>>(
        mean2, (const void*)h1, Wc2, b2, d_out, N2);
}